// Round 1
// baseline (1297.739 us; speedup 1.0000x reference)
//
#include <hip/hip_runtime.h>

#define NN 40000
#define DD 128
#define EE 640000
#define SLOPE 0.01f
#define XP 132   // padded LDS row stride (floats); 132*4=528 B, 16B-multiple

__device__ __forceinline__ float leaky1(float v) { return v >= 0.f ? v : v * SLOPE; }

// ---------------------------------------------------------------------------
// K1: per-node precompute.
//   h     = leaky(x @ Wh1 + bh1)            [N,128]  (LDS only)
//   delta = tanh(h @ Wh2 + bh2)             [N,3]    -> global
//   xf    = x @ Wf1[3:,:] + bf1             [N,128]  -> global
// Block = 256 threads, 32 rows/block. Thread (rg,cg) owns 4 rows x 4 cols.
// ---------------------------------------------------------------------------
__global__ __launch_bounds__(256) void k_node_pre(
    const float* __restrict__ x,
    const float* __restrict__ Wh1, const float* __restrict__ bh1,
    const float* __restrict__ Wh2, const float* __restrict__ bh2,
    const float* __restrict__ Wf1, const float* __restrict__ bf1,
    float* __restrict__ xf, float* __restrict__ delta)
{
    __shared__ float sbuf[32 * XP];   // x tile, then reused for h tile
    const int t    = threadIdx.x;
    const int row0 = blockIdx.x * 32;
    const int cg = t & 31, rg = t >> 5;
    const int c4 = cg * 4, r4 = rg * 4;

    // stage x[row0..row0+31][0..127] into sbuf (row-major, padded)
    #pragma unroll
    for (int q = 0; q < 4; ++q) {
        const int f4 = t + q * 256;          // 0..1023 float4 slots
        const int r  = f4 >> 5;              // 0..31
        const int d4 = (f4 & 31) << 2;       // 0,4,...,124
        const float4 v = *(const float4*)(x + (size_t)(row0 + r) * DD + d4);
        *(float4*)(sbuf + r * XP + d4) = v;
    }
    __syncthreads();

    float hacc[4][4] = {};
    float facc[4][4] = {};
    for (int d = 0; d < DD; ++d) {
        float xa[4];
        #pragma unroll
        for (int i = 0; i < 4; ++i) xa[i] = sbuf[(r4 + i) * XP + d];
        const float4 wh = *(const float4*)(Wh1 + (size_t)d * DD + c4);
        const float4 wf = *(const float4*)(Wf1 + (size_t)(3 + d) * DD + c4);
        const float whv[4] = {wh.x, wh.y, wh.z, wh.w};
        const float wfv[4] = {wf.x, wf.y, wf.z, wf.w};
        #pragma unroll
        for (int i = 0; i < 4; ++i) {
            #pragma unroll
            for (int j = 0; j < 4; ++j) {
                hacc[i][j] += xa[i] * whv[j];
                facc[i][j] += xa[i] * wfv[j];
            }
        }
    }

    // xf -> global (bias folded in; leaky applied per-edge after rel term)
    const float4 bfv = *(const float4*)(bf1 + c4);
    #pragma unroll
    for (int i = 0; i < 4; ++i) {
        float4 fv;
        fv.x = facc[i][0] + bfv.x;
        fv.y = facc[i][1] + bfv.y;
        fv.z = facc[i][2] + bfv.z;
        fv.w = facc[i][3] + bfv.w;
        *(float4*)(xf + (size_t)(row0 + r4 + i) * DD + c4) = fv;
    }

    __syncthreads();   // all x reads done; reuse sbuf for h

    const float4 bhv = *(const float4*)(bh1 + c4);
    #pragma unroll
    for (int i = 0; i < 4; ++i) {
        float4 hv;
        hv.x = leaky1(hacc[i][0] + bhv.x);
        hv.y = leaky1(hacc[i][1] + bhv.y);
        hv.z = leaky1(hacc[i][2] + bhv.z);
        hv.w = leaky1(hacc[i][3] + bhv.w);
        *(float4*)(sbuf + (r4 + i) * XP + c4) = hv;
    }
    __syncthreads();

    // delta = tanh(h @ Wh2 + bh2): 32 rows x 3 outputs = 96 threads
    if (t < 96) {
        const int r = t / 3, k = t - 3 * (t / 3);
        float s = bh2[k];
        for (int d = 0; d < DD; ++d) s += sbuf[r * XP + d] * Wh2[d * 3 + k];
        delta[(size_t)(row0 + r) * 3 + k] = tanhf(s);
    }
}

// ---------------------------------------------------------------------------
// K2: zero aggr (float4 grid-stride)
// ---------------------------------------------------------------------------
__global__ __launch_bounds__(256) void k_zero(float4* __restrict__ p, int n4)
{
    const float4 z = {0.f, 0.f, 0.f, 0.f};
    for (int i = blockIdx.x * 256 + threadIdx.x; i < n4; i += gridDim.x * 256)
        p[i] = z;
}

// ---------------------------------------------------------------------------
// K3: per-edge message + scatter-add.
//   rel = pos[src]-pos[dst]+delta[dst]
//   msg = leaky(xf[src] + rel @ Wf1[0:3,:])
//   aggr[dst] += msg (HW fp32 atomics)
// 32 lanes/edge, 4 cols/lane, 8 edges/block.
// ---------------------------------------------------------------------------
__global__ __launch_bounds__(256) void k_edge(
    const int* __restrict__ ei, const float* __restrict__ pos,
    const float* __restrict__ delta, const float* __restrict__ xf,
    const float* __restrict__ Wf1, float* __restrict__ aggr)
{
    const int t  = threadIdx.x;
    const int e  = blockIdx.x * 8 + (t >> 5);
    const int c4 = (t & 31) * 4;

    const int src = ei[e];
    const int dst = ei[EE + e];

    const float r0 = pos[src * 3 + 0] - pos[dst * 3 + 0] + delta[dst * 3 + 0];
    const float r1 = pos[src * 3 + 1] - pos[dst * 3 + 1] + delta[dst * 3 + 1];
    const float r2 = pos[src * 3 + 2] - pos[dst * 3 + 2] + delta[dst * 3 + 2];

    const float4 xv = *(const float4*)(xf + (size_t)src * DD + c4);
    const float4 w0 = *(const float4*)(Wf1 + 0 * DD + c4);
    const float4 w1 = *(const float4*)(Wf1 + 1 * DD + c4);
    const float4 w2 = *(const float4*)(Wf1 + 2 * DD + c4);

    const float m0 = leaky1(xv.x + r0 * w0.x + r1 * w1.x + r2 * w2.x);
    const float m1 = leaky1(xv.y + r0 * w0.y + r1 * w1.y + r2 * w2.y);
    const float m2 = leaky1(xv.z + r0 * w0.z + r1 * w1.z + r2 * w2.z);
    const float m3 = leaky1(xv.w + r0 * w0.w + r1 * w1.w + r2 * w2.w);

    float* a = aggr + (size_t)dst * DD + c4;
    unsafeAtomicAdd(a + 0, m0);
    unsafeAtomicAdd(a + 1, m1);
    unsafeAtomicAdd(a + 2, m2);
    unsafeAtomicAdd(a + 3, m3);
}

// ---------------------------------------------------------------------------
// K4: node update.
//   g   = leaky(aggr @ Wg1 + bg1)
//   out = x + g @ Wg2 + bg2
// Same tiling as K1; g round-trips through LDS.
// ---------------------------------------------------------------------------
__global__ __launch_bounds__(256) void k_node_out(
    const float* __restrict__ aggr, const float* __restrict__ x,
    const float* __restrict__ Wg1, const float* __restrict__ bg1,
    const float* __restrict__ Wg2, const float* __restrict__ bg2,
    float* __restrict__ out)
{
    __shared__ float sbuf[32 * XP];   // aggr tile, then g tile
    const int t    = threadIdx.x;
    const int row0 = blockIdx.x * 32;
    const int cg = t & 31, rg = t >> 5;
    const int c4 = cg * 4, r4 = rg * 4;

    #pragma unroll
    for (int q = 0; q < 4; ++q) {
        const int f4 = t + q * 256;
        const int r  = f4 >> 5;
        const int d4 = (f4 & 31) << 2;
        const float4 v = *(const float4*)(aggr + (size_t)(row0 + r) * DD + d4);
        *(float4*)(sbuf + r * XP + d4) = v;
    }
    __syncthreads();

    float gacc[4][4] = {};
    for (int d = 0; d < DD; ++d) {
        float av[4];
        #pragma unroll
        for (int i = 0; i < 4; ++i) av[i] = sbuf[(r4 + i) * XP + d];
        const float4 w = *(const float4*)(Wg1 + (size_t)d * DD + c4);
        const float wv[4] = {w.x, w.y, w.z, w.w};
        #pragma unroll
        for (int i = 0; i < 4; ++i)
            #pragma unroll
            for (int j = 0; j < 4; ++j) gacc[i][j] += av[i] * wv[j];
    }
    __syncthreads();   // aggr reads done; reuse sbuf for g

    const float4 b1 = *(const float4*)(bg1 + c4);
    #pragma unroll
    for (int i = 0; i < 4; ++i) {
        float4 gv;
        gv.x = leaky1(gacc[i][0] + b1.x);
        gv.y = leaky1(gacc[i][1] + b1.y);
        gv.z = leaky1(gacc[i][2] + b1.z);
        gv.w = leaky1(gacc[i][3] + b1.w);
        *(float4*)(sbuf + (r4 + i) * XP + c4) = gv;
    }
    __syncthreads();

    float oacc[4][4] = {};
    for (int d = 0; d < DD; ++d) {
        float gv[4];
        #pragma unroll
        for (int i = 0; i < 4; ++i) gv[i] = sbuf[(r4 + i) * XP + d];
        const float4 w = *(const float4*)(Wg2 + (size_t)d * DD + c4);
        const float wv[4] = {w.x, w.y, w.z, w.w};
        #pragma unroll
        for (int i = 0; i < 4; ++i)
            #pragma unroll
            for (int j = 0; j < 4; ++j) oacc[i][j] += gv[i] * wv[j];
    }

    const float4 b2 = *(const float4*)(bg2 + c4);
    #pragma unroll
    for (int i = 0; i < 4; ++i) {
        const size_t off = (size_t)(row0 + r4 + i) * DD + c4;
        const float4 xr = *(const float4*)(x + off);
        float4 ov;
        ov.x = xr.x + oacc[i][0] + b2.x;
        ov.y = xr.y + oacc[i][1] + b2.y;
        ov.z = xr.z + oacc[i][2] + b2.z;
        ov.w = xr.w + oacc[i][3] + b2.w;
        *(float4*)(out + off) = ov;
    }
}

// ---------------------------------------------------------------------------
extern "C" void kernel_launch(void* const* d_in, const int* in_sizes, int n_in,
                              void* d_out, int out_size, void* d_ws, size_t ws_size,
                              hipStream_t stream)
{
    const float* x   = (const float*)d_in[0];
    const float* pos = (const float*)d_in[1];
    const int*   ei  = (const int*)d_in[2];
    const float* Wh1 = (const float*)d_in[3];
    const float* bh1 = (const float*)d_in[4];
    const float* Wh2 = (const float*)d_in[5];
    const float* bh2 = (const float*)d_in[6];
    const float* Wf1 = (const float*)d_in[7];
    const float* bf1 = (const float*)d_in[8];
    const float* Wg1 = (const float*)d_in[9];
    const float* bg1 = (const float*)d_in[10];
    const float* Wg2 = (const float*)d_in[11];
    const float* bg2 = (const float*)d_in[12];
    float* out = (float*)d_out;

    float* xf    = (float*)d_ws;                       // N*128
    float* delta = xf + (size_t)NN * DD;               // N*3
    float* aggr  = delta + (size_t)NN * 3;             // N*128

    k_node_pre<<<NN / 32, 256, 0, stream>>>(x, Wh1, bh1, Wh2, bh2, Wf1, bf1, xf, delta);
    k_zero<<<1280, 256, 0, stream>>>((float4*)aggr, NN * DD / 4);
    k_edge<<<EE / 8, 256, 0, stream>>>(ei, pos, delta, xf, Wf1, aggr);
    k_node_out<<<NN / 32, 256, 0, stream>>>(aggr, x, Wg1, bg1, Wg2, bg2, out);
}

// Round 2
// 419.722 us; speedup vs baseline: 3.0919x; 3.0919x over previous
//
#include <hip/hip_runtime.h>

#define NN 40000
#define DD 128
#define EE 640000
#define SLOPE 0.01f
#define XP 132   // padded LDS row stride (floats)

__device__ __forceinline__ float leaky1(float v) { return v >= 0.f ? v : v * SLOPE; }

// ---------------------------------------------------------------------------
// K1: per-node precompute.
//   h     = leaky(x @ Wh1 + bh1)            (LDS only)
//   delta = tanh(h @ Wh2 + bh2)             -> global
//   xf    = x @ Wf1[3:,:] + bf1             -> global
// ---------------------------------------------------------------------------
__global__ __launch_bounds__(256) void k_node_pre(
    const float* __restrict__ x,
    const float* __restrict__ Wh1, const float* __restrict__ bh1,
    const float* __restrict__ Wh2, const float* __restrict__ bh2,
    const float* __restrict__ Wf1, const float* __restrict__ bf1,
    float* __restrict__ xf, float* __restrict__ delta)
{
    __shared__ float sbuf[32 * XP];
    const int t    = threadIdx.x;
    const int row0 = blockIdx.x * 32;
    const int cg = t & 31, rg = t >> 5;
    const int c4 = cg * 4, r4 = rg * 4;

    #pragma unroll
    for (int q = 0; q < 4; ++q) {
        const int f4 = t + q * 256;
        const int r  = f4 >> 5;
        const int d4 = (f4 & 31) << 2;
        const float4 v = *(const float4*)(x + (size_t)(row0 + r) * DD + d4);
        *(float4*)(sbuf + r * XP + d4) = v;
    }
    __syncthreads();

    float hacc[4][4] = {};
    float facc[4][4] = {};
    for (int d = 0; d < DD; ++d) {
        float xa[4];
        #pragma unroll
        for (int i = 0; i < 4; ++i) xa[i] = sbuf[(r4 + i) * XP + d];
        const float4 wh = *(const float4*)(Wh1 + (size_t)d * DD + c4);
        const float4 wf = *(const float4*)(Wf1 + (size_t)(3 + d) * DD + c4);
        const float whv[4] = {wh.x, wh.y, wh.z, wh.w};
        const float wfv[4] = {wf.x, wf.y, wf.z, wf.w};
        #pragma unroll
        for (int i = 0; i < 4; ++i) {
            #pragma unroll
            for (int j = 0; j < 4; ++j) {
                hacc[i][j] += xa[i] * whv[j];
                facc[i][j] += xa[i] * wfv[j];
            }
        }
    }

    const float4 bfv = *(const float4*)(bf1 + c4);
    #pragma unroll
    for (int i = 0; i < 4; ++i) {
        float4 fv;
        fv.x = facc[i][0] + bfv.x;
        fv.y = facc[i][1] + bfv.y;
        fv.z = facc[i][2] + bfv.z;
        fv.w = facc[i][3] + bfv.w;
        *(float4*)(xf + (size_t)(row0 + r4 + i) * DD + c4) = fv;
    }

    __syncthreads();

    const float4 bhv = *(const float4*)(bh1 + c4);
    #pragma unroll
    for (int i = 0; i < 4; ++i) {
        float4 hv;
        hv.x = leaky1(hacc[i][0] + bhv.x);
        hv.y = leaky1(hacc[i][1] + bhv.y);
        hv.z = leaky1(hacc[i][2] + bhv.z);
        hv.w = leaky1(hacc[i][3] + bhv.w);
        *(float4*)(sbuf + (r4 + i) * XP + c4) = hv;
    }
    __syncthreads();

    if (t < 96) {
        const int r = t / 3, k = t - 3 * (t / 3);
        float s = bh2[k];
        for (int d = 0; d < DD; ++d) s += sbuf[r * XP + d] * Wh2[d * 3 + k];
        delta[(size_t)(row0 + r) * 3 + k] = tanhf(s);
    }
}

// ---------------------------------------------------------------------------
// K_zero: zero an int/float region (16B granular)
// ---------------------------------------------------------------------------
__global__ __launch_bounds__(256) void k_zero(float4* __restrict__ p, int n4)
{
    const float4 z = {0.f, 0.f, 0.f, 0.f};
    for (int i = blockIdx.x * 256 + threadIdx.x; i < n4; i += gridDim.x * 256)
        p[i] = z;
}

// ---------------------------------------------------------------------------
// K_hist: deg[dst]++ for each edge
// ---------------------------------------------------------------------------
__global__ __launch_bounds__(256) void k_hist(const int* __restrict__ ei,
                                              int* __restrict__ deg)
{
    const int e = blockIdx.x * 256 + threadIdx.x;
    atomicAdd(&deg[ei[EE + e]], 1);
}

// ---------------------------------------------------------------------------
// K_scan: exclusive scan of deg[NN] -> off[NN+1]; also copy to cursor.
// Single block, 1024 threads, 40 elems/thread.
// ---------------------------------------------------------------------------
__global__ __launch_bounds__(1024) void k_scan(const int* __restrict__ deg,
                                               int* __restrict__ off,
                                               int* __restrict__ cur)
{
    __shared__ int wsum[16];
    const int t = threadIdx.x;
    const int base = t * 40;

    int s = 0;
    for (int k = 0; k < 40; ++k) {
        const int i = base + k;
        if (i < NN) s += deg[i];
    }
    const int lane = t & 63, w = t >> 6;
    int incl = s;
    #pragma unroll
    for (int d = 1; d < 64; d <<= 1) {
        const int o = __shfl_up(incl, d);
        if (lane >= d) incl += o;
    }
    if (lane == 63) wsum[w] = incl;
    __syncthreads();
    int wbase = 0;
    for (int i = 0; i < w; ++i) wbase += wsum[i];
    const int excl = wbase + incl - s;

    int run = excl;
    for (int k = 0; k < 40; ++k) {
        const int i = base + k;
        if (i < NN) { off[i] = run; cur[i] = run; run += deg[i]; }
    }
    if (t == 1023) off[NN] = excl;   // chunks past NN contribute 0 -> excl == E
}

// ---------------------------------------------------------------------------
// K_scatter: bucket src indices by dst (CSR fill)
// ---------------------------------------------------------------------------
__global__ __launch_bounds__(256) void k_scatter(const int* __restrict__ ei,
                                                 int* __restrict__ cur,
                                                 int* __restrict__ esrc)
{
    const int e = blockIdx.x * 256 + threadIdx.x;
    const int src = ei[e];
    const int dst = ei[EE + e];
    const int p = atomicAdd(&cur[dst], 1);
    esrc[p] = src;
}

// ---------------------------------------------------------------------------
// K_gather: pull-mode aggregation. One wave (64 lanes) per dst node,
// 2 cols/lane. aggr row written exactly once (no atomics, no pre-zero).
//   aggr[n] = sum_e leaky(xf[src_e] + rel_e @ Wf1[0:3,:])
//   rel_e   = pos[src_e] + (delta[n] - pos[n])
// ---------------------------------------------------------------------------
__global__ __launch_bounds__(256) void k_gather(
    const int* __restrict__ off, const int* __restrict__ esrc,
    const float* __restrict__ pos, const float* __restrict__ delta,
    const float* __restrict__ xf, const float* __restrict__ Wf1,
    float* __restrict__ aggr)
{
    const int t    = threadIdx.x;
    const int lane = t & 63;
    const int n    = blockIdx.x * 4 + (t >> 6);
    const int c2   = lane * 2;

    const float2 w0 = *(const float2*)(Wf1 + 0 * DD + c2);
    const float2 w1 = *(const float2*)(Wf1 + 1 * DD + c2);
    const float2 w2 = *(const float2*)(Wf1 + 2 * DD + c2);

    const float q0 = delta[n * 3 + 0] - pos[n * 3 + 0];
    const float q1 = delta[n * 3 + 1] - pos[n * 3 + 1];
    const float q2 = delta[n * 3 + 2] - pos[n * 3 + 2];

    float a0 = 0.f, a1 = 0.f;
    const int beg = off[n], end = off[n + 1];

    int j = beg;
    for (; j + 1 < end; j += 2) {
        const int s0 = esrc[j];
        const int s1 = esrc[j + 1];
        const float2 xv0 = *(const float2*)(xf + (size_t)s0 * DD + c2);
        const float2 xv1 = *(const float2*)(xf + (size_t)s1 * DD + c2);
        const float r00 = pos[s0 * 3 + 0] + q0;
        const float r01 = pos[s0 * 3 + 1] + q1;
        const float r02 = pos[s0 * 3 + 2] + q2;
        const float r10 = pos[s1 * 3 + 0] + q0;
        const float r11 = pos[s1 * 3 + 1] + q1;
        const float r12 = pos[s1 * 3 + 2] + q2;
        a0 += leaky1(xv0.x + r00 * w0.x + r01 * w1.x + r02 * w2.x);
        a1 += leaky1(xv0.y + r00 * w0.y + r01 * w1.y + r02 * w2.y);
        a0 += leaky1(xv1.x + r10 * w0.x + r11 * w1.x + r12 * w2.x);
        a1 += leaky1(xv1.y + r10 * w0.y + r11 * w1.y + r12 * w2.y);
    }
    if (j < end) {
        const int s0 = esrc[j];
        const float2 xv0 = *(const float2*)(xf + (size_t)s0 * DD + c2);
        const float r00 = pos[s0 * 3 + 0] + q0;
        const float r01 = pos[s0 * 3 + 1] + q1;
        const float r02 = pos[s0 * 3 + 2] + q2;
        a0 += leaky1(xv0.x + r00 * w0.x + r01 * w1.x + r02 * w2.x);
        a1 += leaky1(xv0.y + r00 * w0.y + r01 * w1.y + r02 * w2.y);
    }

    float2 res; res.x = a0; res.y = a1;
    *(float2*)(aggr + (size_t)n * DD + c2) = res;
}

// ---------------------------------------------------------------------------
// K4: node update.  out = x + leaky(aggr@Wg1+bg1) @ Wg2 + bg2
// ---------------------------------------------------------------------------
__global__ __launch_bounds__(256) void k_node_out(
    const float* __restrict__ aggr, const float* __restrict__ x,
    const float* __restrict__ Wg1, const float* __restrict__ bg1,
    const float* __restrict__ Wg2, const float* __restrict__ bg2,
    float* __restrict__ out)
{
    __shared__ float sbuf[32 * XP];
    const int t    = threadIdx.x;
    const int row0 = blockIdx.x * 32;
    const int cg = t & 31, rg = t >> 5;
    const int c4 = cg * 4, r4 = rg * 4;

    #pragma unroll
    for (int q = 0; q < 4; ++q) {
        const int f4 = t + q * 256;
        const int r  = f4 >> 5;
        const int d4 = (f4 & 31) << 2;
        const float4 v = *(const float4*)(aggr + (size_t)(row0 + r) * DD + d4);
        *(float4*)(sbuf + r * XP + d4) = v;
    }
    __syncthreads();

    float gacc[4][4] = {};
    for (int d = 0; d < DD; ++d) {
        float av[4];
        #pragma unroll
        for (int i = 0; i < 4; ++i) av[i] = sbuf[(r4 + i) * XP + d];
        const float4 w = *(const float4*)(Wg1 + (size_t)d * DD + c4);
        const float wv[4] = {w.x, w.y, w.z, w.w};
        #pragma unroll
        for (int i = 0; i < 4; ++i)
            #pragma unroll
            for (int j = 0; j < 4; ++j) gacc[i][j] += av[i] * wv[j];
    }
    __syncthreads();

    const float4 b1 = *(const float4*)(bg1 + c4);
    #pragma unroll
    for (int i = 0; i < 4; ++i) {
        float4 gv;
        gv.x = leaky1(gacc[i][0] + b1.x);
        gv.y = leaky1(gacc[i][1] + b1.y);
        gv.z = leaky1(gacc[i][2] + b1.z);
        gv.w = leaky1(gacc[i][3] + b1.w);
        *(float4*)(sbuf + (r4 + i) * XP + c4) = gv;
    }
    __syncthreads();

    float oacc[4][4] = {};
    for (int d = 0; d < DD; ++d) {
        float gv[4];
        #pragma unroll
        for (int i = 0; i < 4; ++i) gv[i] = sbuf[(r4 + i) * XP + d];
        const float4 w = *(const float4*)(Wg2 + (size_t)d * DD + c4);
        const float wv[4] = {w.x, w.y, w.z, w.w};
        #pragma unroll
        for (int i = 0; i < 4; ++i)
            #pragma unroll
            for (int j = 0; j < 4; ++j) oacc[i][j] += gv[i] * wv[j];
    }

    const float4 b2 = *(const float4*)(bg2 + c4);
    #pragma unroll
    for (int i = 0; i < 4; ++i) {
        const size_t off2 = (size_t)(row0 + r4 + i) * DD + c4;
        const float4 xr = *(const float4*)(x + off2);
        float4 ov;
        ov.x = xr.x + oacc[i][0] + b2.x;
        ov.y = xr.y + oacc[i][1] + b2.y;
        ov.z = xr.z + oacc[i][2] + b2.z;
        ov.w = xr.w + oacc[i][3] + b2.w;
        *(float4*)(out + off2) = ov;
    }
}

// ---------------------------------------------------------------------------
extern "C" void kernel_launch(void* const* d_in, const int* in_sizes, int n_in,
                              void* d_out, int out_size, void* d_ws, size_t ws_size,
                              hipStream_t stream)
{
    const float* x   = (const float*)d_in[0];
    const float* pos = (const float*)d_in[1];
    const int*   ei  = (const int*)d_in[2];
    const float* Wh1 = (const float*)d_in[3];
    const float* bh1 = (const float*)d_in[4];
    const float* Wh2 = (const float*)d_in[5];
    const float* bh2 = (const float*)d_in[6];
    const float* Wf1 = (const float*)d_in[7];
    const float* bf1 = (const float*)d_in[8];
    const float* Wg1 = (const float*)d_in[9];
    const float* bg1 = (const float*)d_in[10];
    const float* Wg2 = (const float*)d_in[11];
    const float* bg2 = (const float*)d_in[12];
    float* out = (float*)d_out;

    // workspace layout (floats/ints, 4 B each):
    float* xf    = (float*)d_ws;                    // NN*DD           = 5.12 M
    float* aggr  = xf + (size_t)NN * DD;            // NN*DD           = 5.12 M
    float* delta = aggr + (size_t)NN * DD;          // NN*3
    int*   deg   = (int*)(delta + (size_t)NN * 3);  // NN   (zeroed; becomes off-source)
    int*   off   = deg + NN;                        // NN+1
    int*   cur   = off + NN + 1;                    // NN
    int*   esrc  = cur + NN;                        // EE
    // total ~11.16 M elems = 44.6 MB

    k_zero<<<40, 256, 0, stream>>>((float4*)deg, NN / 4);
    k_node_pre<<<NN / 32, 256, 0, stream>>>(x, Wh1, bh1, Wh2, bh2, Wf1, bf1, xf, delta);
    k_hist<<<EE / 256, 256, 0, stream>>>(ei, deg);
    k_scan<<<1, 1024, 0, stream>>>(deg, off, cur);
    k_scatter<<<EE / 256, 256, 0, stream>>>(ei, cur, esrc);
    k_gather<<<NN / 4, 256, 0, stream>>>(off, esrc, pos, delta, xf, Wf1, aggr);
    k_node_out<<<NN / 32, 256, 0, stream>>>(aggr, x, Wg1, bg1, Wg2, bg2, out);
}

// Round 3
// 305.353 us; speedup vs baseline: 4.2500x; 1.3746x over previous
//
#include <hip/hip_runtime.h>

#define NN 40000
#define DD 128
#define EE 640000
#define SLOPE 0.01f
#define XP 132   // padded LDS row stride (floats)

__device__ __forceinline__ float leaky1(float v) { return v >= 0.f ? v : v * SLOPE; }

// ---------------------------------------------------------------------------
// K1: per-node precompute + fused edge histogram.
//   deg[dst]++ for 2 edges/thread (atomic pipe, overlaps VALU work)
//   h     = leaky(x @ Wh1 + bh1)            (LDS only)
//   delta = tanh(h @ Wh2 + bh2)             -> global
//   xf    = x @ Wf1[3:,:] + bf1             -> global
// ---------------------------------------------------------------------------
__global__ __launch_bounds__(256) void k_node_pre(
    const float* __restrict__ x,
    const float* __restrict__ Wh1, const float* __restrict__ bh1,
    const float* __restrict__ Wh2, const float* __restrict__ bh2,
    const float* __restrict__ Wf1, const float* __restrict__ bf1,
    const int* __restrict__ ei, int* __restrict__ deg,
    float* __restrict__ xf, float* __restrict__ delta)
{
    __shared__ float sbuf[32 * XP];
    const int t    = threadIdx.x;
    const int row0 = blockIdx.x * 32;
    const int cg = t & 31, rg = t >> 5;
    const int c4 = cg * 4, r4 = rg * 4;

    // fused histogram: 2 edges per thread, fire-and-forget atomics
    {
        const int gid = blockIdx.x * 256 + t;
        const int e0 = gid * 2;
        atomicAdd(&deg[ei[EE + e0]], 1);
        atomicAdd(&deg[ei[EE + e0 + 1]], 1);
    }

    #pragma unroll
    for (int q = 0; q < 4; ++q) {
        const int f4 = t + q * 256;
        const int r  = f4 >> 5;
        const int d4 = (f4 & 31) << 2;
        const float4 v = *(const float4*)(x + (size_t)(row0 + r) * DD + d4);
        *(float4*)(sbuf + r * XP + d4) = v;
    }
    __syncthreads();

    float hacc[4][4] = {};
    float facc[4][4] = {};
    for (int d = 0; d < DD; ++d) {
        float xa[4];
        #pragma unroll
        for (int i = 0; i < 4; ++i) xa[i] = sbuf[(r4 + i) * XP + d];
        const float4 wh = *(const float4*)(Wh1 + (size_t)d * DD + c4);
        const float4 wf = *(const float4*)(Wf1 + (size_t)(3 + d) * DD + c4);
        const float whv[4] = {wh.x, wh.y, wh.z, wh.w};
        const float wfv[4] = {wf.x, wf.y, wf.z, wf.w};
        #pragma unroll
        for (int i = 0; i < 4; ++i) {
            #pragma unroll
            for (int j = 0; j < 4; ++j) {
                hacc[i][j] += xa[i] * whv[j];
                facc[i][j] += xa[i] * wfv[j];
            }
        }
    }

    const float4 bfv = *(const float4*)(bf1 + c4);
    #pragma unroll
    for (int i = 0; i < 4; ++i) {
        float4 fv;
        fv.x = facc[i][0] + bfv.x;
        fv.y = facc[i][1] + bfv.y;
        fv.z = facc[i][2] + bfv.z;
        fv.w = facc[i][3] + bfv.w;
        *(float4*)(xf + (size_t)(row0 + r4 + i) * DD + c4) = fv;
    }

    __syncthreads();

    const float4 bhv = *(const float4*)(bh1 + c4);
    #pragma unroll
    for (int i = 0; i < 4; ++i) {
        float4 hv;
        hv.x = leaky1(hacc[i][0] + bhv.x);
        hv.y = leaky1(hacc[i][1] + bhv.y);
        hv.z = leaky1(hacc[i][2] + bhv.z);
        hv.w = leaky1(hacc[i][3] + bhv.w);
        *(float4*)(sbuf + (r4 + i) * XP + c4) = hv;
    }
    __syncthreads();

    if (t < 96) {
        const int r = t / 3, k = t - 3 * (t / 3);
        float s = bh2[k];
        for (int d = 0; d < DD; ++d) s += sbuf[r * XP + d] * Wh2[d * 3 + k];
        delta[(size_t)(row0 + r) * 3 + k] = tanhf(s);
    }
}

// ---------------------------------------------------------------------------
// K_zero: zero a region (16B granular)
// ---------------------------------------------------------------------------
__global__ __launch_bounds__(256) void k_zero(float4* __restrict__ p, int n4)
{
    const float4 z = {0.f, 0.f, 0.f, 0.f};
    for (int i = blockIdx.x * 256 + threadIdx.x; i < n4; i += gridDim.x * 256)
        p[i] = z;
}

// ---------------------------------------------------------------------------
// Hierarchical exclusive scan of deg[NN] -> off[NN+1] (+cur copy).
// up:  40 blocks x 1024; block-local exclusive scan in-place into off,
//      block totals into bsum[40]
// mid: 1 wave scans bsum -> bbase (exclusive)
// add: off[i] += bbase[blk]; cur[i] = off[i]; off[NN] = EE
// ---------------------------------------------------------------------------
__global__ __launch_bounds__(1024) void k_scan_up(const int* __restrict__ deg,
                                                  int* __restrict__ off,
                                                  int* __restrict__ bsum)
{
    __shared__ int wsum[16];
    const int t = threadIdx.x, b = blockIdx.x;
    const int i = b * 1024 + t;
    const int v = (i < NN) ? deg[i] : 0;
    const int lane = t & 63, w = t >> 6;

    int incl = v;
    #pragma unroll
    for (int d = 1; d < 64; d <<= 1) {
        const int o = __shfl_up(incl, d);
        if (lane >= d) incl += o;
    }
    if (lane == 63) wsum[w] = incl;
    __syncthreads();
    int wbase = 0;
    for (int k = 0; k < w; ++k) wbase += wsum[k];

    if (i < NN) off[i] = wbase + incl - v;
    if (t == 1023) bsum[b] = wbase + incl;
}

__global__ __launch_bounds__(64) void k_scan_mid(const int* __restrict__ bsum,
                                                 int* __restrict__ bbase)
{
    const int t = threadIdx.x;
    const int v = (t < 40) ? bsum[t] : 0;
    int incl = v;
    #pragma unroll
    for (int d = 1; d < 64; d <<= 1) {
        const int o = __shfl_up(incl, d);
        if (t >= d) incl += o;
    }
    if (t < 40) bbase[t] = incl - v;
}

__global__ __launch_bounds__(1024) void k_scan_add(int* __restrict__ off,
                                                   const int* __restrict__ bbase,
                                                   int* __restrict__ cur)
{
    const int t = threadIdx.x, b = blockIdx.x;
    const int i = b * 1024 + t;
    if (i < NN) {
        const int o = off[i] + bbase[b];
        off[i] = o;
        cur[i] = o;
    }
    if (i == 0) off[NN] = EE;
}

// ---------------------------------------------------------------------------
// K_scatter: bucket src indices by dst (CSR fill)
// ---------------------------------------------------------------------------
__global__ __launch_bounds__(256) void k_scatter(const int* __restrict__ ei,
                                                 int* __restrict__ cur,
                                                 int* __restrict__ esrc)
{
    const int e = blockIdx.x * 256 + threadIdx.x;
    const int src = ei[e];
    const int dst = ei[EE + e];
    const int p = atomicAdd(&cur[dst], 1);
    esrc[p] = src;
}

// ---------------------------------------------------------------------------
// K_gather: pull-mode aggregation. One wave per dst node, 2 cols/lane.
//   aggr[n] = sum_e leaky(xf[src_e] + rel_e @ Wf1[0:3,:])
//   rel_e   = pos[src_e] + (delta[n] - pos[n])
// ---------------------------------------------------------------------------
__global__ __launch_bounds__(256) void k_gather(
    const int* __restrict__ off, const int* __restrict__ esrc,
    const float* __restrict__ pos, const float* __restrict__ delta,
    const float* __restrict__ xf, const float* __restrict__ Wf1,
    float* __restrict__ aggr)
{
    const int t    = threadIdx.x;
    const int lane = t & 63;
    const int n    = blockIdx.x * 4 + (t >> 6);
    const int c2   = lane * 2;

    const float2 w0 = *(const float2*)(Wf1 + 0 * DD + c2);
    const float2 w1 = *(const float2*)(Wf1 + 1 * DD + c2);
    const float2 w2 = *(const float2*)(Wf1 + 2 * DD + c2);

    const float q0 = delta[n * 3 + 0] - pos[n * 3 + 0];
    const float q1 = delta[n * 3 + 1] - pos[n * 3 + 1];
    const float q2 = delta[n * 3 + 2] - pos[n * 3 + 2];

    float a0 = 0.f, a1 = 0.f;
    const int beg = off[n], end = off[n + 1];

    int j = beg;
    for (; j + 1 < end; j += 2) {
        const int s0 = esrc[j];
        const int s1 = esrc[j + 1];
        const float2 xv0 = *(const float2*)(xf + (size_t)s0 * DD + c2);
        const float2 xv1 = *(const float2*)(xf + (size_t)s1 * DD + c2);
        const float r00 = pos[s0 * 3 + 0] + q0;
        const float r01 = pos[s0 * 3 + 1] + q1;
        const float r02 = pos[s0 * 3 + 2] + q2;
        const float r10 = pos[s1 * 3 + 0] + q0;
        const float r11 = pos[s1 * 3 + 1] + q1;
        const float r12 = pos[s1 * 3 + 2] + q2;
        a0 += leaky1(xv0.x + r00 * w0.x + r01 * w1.x + r02 * w2.x);
        a1 += leaky1(xv0.y + r00 * w0.y + r01 * w1.y + r02 * w2.y);
        a0 += leaky1(xv1.x + r10 * w0.x + r11 * w1.x + r12 * w2.x);
        a1 += leaky1(xv1.y + r10 * w0.y + r11 * w1.y + r12 * w2.y);
    }
    if (j < end) {
        const int s0 = esrc[j];
        const float2 xv0 = *(const float2*)(xf + (size_t)s0 * DD + c2);
        const float r00 = pos[s0 * 3 + 0] + q0;
        const float r01 = pos[s0 * 3 + 1] + q1;
        const float r02 = pos[s0 * 3 + 2] + q2;
        a0 += leaky1(xv0.x + r00 * w0.x + r01 * w1.x + r02 * w2.x);
        a1 += leaky1(xv0.y + r00 * w0.y + r01 * w1.y + r02 * w2.y);
    }

    float2 res; res.x = a0; res.y = a1;
    *(float2*)(aggr + (size_t)n * DD + c2) = res;
}

// ---------------------------------------------------------------------------
// K4: node update.  out = x + leaky(aggr@Wg1+bg1) @ Wg2 + bg2
// ---------------------------------------------------------------------------
__global__ __launch_bounds__(256) void k_node_out(
    const float* __restrict__ aggr, const float* __restrict__ x,
    const float* __restrict__ Wg1, const float* __restrict__ bg1,
    const float* __restrict__ Wg2, const float* __restrict__ bg2,
    float* __restrict__ out)
{
    __shared__ float sbuf[32 * XP];
    const int t    = threadIdx.x;
    const int row0 = blockIdx.x * 32;
    const int cg = t & 31, rg = t >> 5;
    const int c4 = cg * 4, r4 = rg * 4;

    #pragma unroll
    for (int q = 0; q < 4; ++q) {
        const int f4 = t + q * 256;
        const int r  = f4 >> 5;
        const int d4 = (f4 & 31) << 2;
        const float4 v = *(const float4*)(aggr + (size_t)(row0 + r) * DD + d4);
        *(float4*)(sbuf + r * XP + d4) = v;
    }
    __syncthreads();

    float gacc[4][4] = {};
    for (int d = 0; d < DD; ++d) {
        float av[4];
        #pragma unroll
        for (int i = 0; i < 4; ++i) av[i] = sbuf[(r4 + i) * XP + d];
        const float4 w = *(const float4*)(Wg1 + (size_t)d * DD + c4);
        const float wv[4] = {w.x, w.y, w.z, w.w};
        #pragma unroll
        for (int i = 0; i < 4; ++i)
            #pragma unroll
            for (int j = 0; j < 4; ++j) gacc[i][j] += av[i] * wv[j];
    }
    __syncthreads();

    const float4 b1 = *(const float4*)(bg1 + c4);
    #pragma unroll
    for (int i = 0; i < 4; ++i) {
        float4 gv;
        gv.x = leaky1(gacc[i][0] + b1.x);
        gv.y = leaky1(gacc[i][1] + b1.y);
        gv.z = leaky1(gacc[i][2] + b1.z);
        gv.w = leaky1(gacc[i][3] + b1.w);
        *(float4*)(sbuf + (r4 + i) * XP + c4) = gv;
    }
    __syncthreads();

    float oacc[4][4] = {};
    for (int d = 0; d < DD; ++d) {
        float gv[4];
        #pragma unroll
        for (int i = 0; i < 4; ++i) gv[i] = sbuf[(r4 + i) * XP + d];
        const float4 w = *(const float4*)(Wg2 + (size_t)d * DD + c4);
        const float wv[4] = {w.x, w.y, w.z, w.w};
        #pragma unroll
        for (int i = 0; i < 4; ++i)
            #pragma unroll
            for (int j = 0; j < 4; ++j) oacc[i][j] += gv[i] * wv[j];
    }

    const float4 b2 = *(const float4*)(bg2 + c4);
    #pragma unroll
    for (int i = 0; i < 4; ++i) {
        const size_t off2 = (size_t)(row0 + r4 + i) * DD + c4;
        const float4 xr = *(const float4*)(x + off2);
        float4 ov;
        ov.x = xr.x + oacc[i][0] + b2.x;
        ov.y = xr.y + oacc[i][1] + b2.y;
        ov.z = xr.z + oacc[i][2] + b2.z;
        ov.w = xr.w + oacc[i][3] + b2.w;
        *(float4*)(out + off2) = ov;
    }
}

// ---------------------------------------------------------------------------
extern "C" void kernel_launch(void* const* d_in, const int* in_sizes, int n_in,
                              void* d_out, int out_size, void* d_ws, size_t ws_size,
                              hipStream_t stream)
{
    const float* x   = (const float*)d_in[0];
    const float* pos = (const float*)d_in[1];
    const int*   ei  = (const int*)d_in[2];
    const float* Wh1 = (const float*)d_in[3];
    const float* bh1 = (const float*)d_in[4];
    const float* Wh2 = (const float*)d_in[5];
    const float* bh2 = (const float*)d_in[6];
    const float* Wf1 = (const float*)d_in[7];
    const float* bf1 = (const float*)d_in[8];
    const float* Wg1 = (const float*)d_in[9];
    const float* bg1 = (const float*)d_in[10];
    const float* Wg2 = (const float*)d_in[11];
    const float* bg2 = (const float*)d_in[12];
    float* out = (float*)d_out;

    // workspace layout (4 B elems):
    float* xf    = (float*)d_ws;                    // NN*DD
    float* aggr  = xf + (size_t)NN * DD;            // NN*DD
    float* delta = aggr + (size_t)NN * DD;          // NN*3
    int*   deg   = (int*)(delta + (size_t)NN * 3);  // NN
    int*   off   = deg + NN;                        // NN+1
    int*   cur   = off + NN + 1;                    // NN
    int*   esrc  = cur + NN;                        // EE
    int*   bsum  = esrc + EE;                       // 40
    int*   bbase = bsum + 40;                       // 40
    // total ~11.16 M elems = 44.6 MB

    k_zero<<<40, 256, 0, stream>>>((float4*)deg, NN / 4);
    k_node_pre<<<NN / 32, 256, 0, stream>>>(x, Wh1, bh1, Wh2, bh2, Wf1, bf1,
                                            ei, deg, xf, delta);
    k_scan_up<<<40, 1024, 0, stream>>>(deg, off, bsum);
    k_scan_mid<<<1, 64, 0, stream>>>(bsum, bbase);
    k_scan_add<<<40, 1024, 0, stream>>>(off, bbase, cur);
    k_scatter<<<EE / 256, 256, 0, stream>>>(ei, cur, esrc);
    k_gather<<<NN / 4, 256, 0, stream>>>(off, esrc, pos, delta, xf, Wf1, aggr);
    k_node_out<<<NN / 32, 256, 0, stream>>>(aggr, x, Wg1, bg1, Wg2, bg2, out);
}

// Round 4
// 243.869 us; speedup vs baseline: 5.3215x; 1.2521x over previous
//
#include <hip/hip_runtime.h>

#define NN 40000
#define DD 128
#define EE 640000
#define SLOPE 0.01f

typedef __attribute__((ext_vector_type(8))) short  short8;   // 8 x bf16 (4 VGPR)
typedef __attribute__((ext_vector_type(8))) unsigned short ushort8;
typedef __attribute__((ext_vector_type(4))) float  floatx4;  // MFMA acc

__device__ __forceinline__ float leaky1(float v) { return v >= 0.f ? v : v * SLOPE; }

__device__ __forceinline__ unsigned short f2bf(float f) {
    unsigned int u = __float_as_uint(f);
    u += 0x7fffu + ((u >> 16) & 1u);       // RNE
    return (unsigned short)(u >> 16);
}

// ---------------------------------------------------------------------------
// K_zero: zero a region (16B granular)
// ---------------------------------------------------------------------------
__global__ __launch_bounds__(256) void k_zero(float4* __restrict__ p, int n4)
{
    const float4 z = {0.f, 0.f, 0.f, 0.f};
    for (int i = blockIdx.x * 256 + threadIdx.x; i < n4; i += gridDim.x * 256)
        p[i] = z;
}

// ---------------------------------------------------------------------------
// K_pack: rearrange the 4 weight matrices (fp32 [K=128][N=128] row-major;
// Wf1 uses rows 3..130) into bf16 MFMA B-fragment order:
//   pk[mat][ct][kc][lane][j] = W[kc*32 + (lane>>4)*8 + j][ct*16 + (lane&15)]
// so a wave's b-frag is ONE coalesced 16B load per lane.
// mats: 0=Wh1, 1=Wf1[3:], 2=Wg1, 3=Wg2.   8192 threads total.
// ---------------------------------------------------------------------------
__global__ __launch_bounds__(256) void k_pack(
    const float* __restrict__ Wh1, const float* __restrict__ Wf1,
    const float* __restrict__ Wg1, const float* __restrict__ Wg2,
    unsigned short* __restrict__ pk)
{
    const int t   = blockIdx.x * 256 + threadIdx.x;   // 0..8191
    const int mat = t >> 11;
    const int rem = t & 2047;
    const int ct  = rem >> 8;
    const int kc  = (rem >> 6) & 3;
    const int l   = rem & 63;
    const float* W = (mat == 0) ? Wh1 : (mat == 1) ? (Wf1 + 3 * DD)
                   : (mat == 2) ? Wg1 : Wg2;
    const int n  = ct * 16 + (l & 15);
    const int k0 = kc * 32 + (l >> 4) * 8;
    ushort8 v;
    #pragma unroll
    for (int j = 0; j < 8; ++j) v[j] = f2bf(W[(size_t)(k0 + j) * DD + n]);
    *(ushort8*)(pk + (size_t)t * 8) = v;
}

// ---------------------------------------------------------------------------
// K_xcvt_hist: x -> bf16 (xb), fused deg[dst]++ histogram.
// 320000 threads: 16 floats each + 2 edges each.
// ---------------------------------------------------------------------------
__global__ __launch_bounds__(256) void k_xcvt_hist(
    const float* __restrict__ x, const int* __restrict__ ei,
    unsigned short* __restrict__ xb, int* __restrict__ deg)
{
    const int gid = blockIdx.x * 256 + threadIdx.x;

    const int e0 = gid * 2;
    atomicAdd(&deg[ei[EE + e0]], 1);
    atomicAdd(&deg[ei[EE + e0 + 1]], 1);

    const size_t base = (size_t)gid * 16;
    ushort8 o0, o1;
    #pragma unroll
    for (int q = 0; q < 2; ++q) {
        #pragma unroll
        for (int p = 0; p < 2; ++p) {
            const float4 v = *(const float4*)(x + base + q * 8 + p * 4);
            ushort8& o = q ? o1 : o0;
            o[p * 4 + 0] = f2bf(v.x);
            o[p * 4 + 1] = f2bf(v.y);
            o[p * 4 + 2] = f2bf(v.z);
            o[p * 4 + 3] = f2bf(v.w);
        }
    }
    *(ushort8*)(xb + base)     = o0;
    *(ushort8*)(xb + base + 8) = o1;
}

// ---------------------------------------------------------------------------
// K1: per-node precompute via MFMA (bf16 in, fp32 acc).
//   h     = leaky(x@Wh1 + bh1)   -> LDS (fp32) for delta
//   delta = tanh(h@Wh2 + bh2)    -> global
//   xfb   = bf16(x@Wf1[3:] + bf1)-> global
// Block = 256 (4 waves), 64 rows/block, wave w owns rows w*16..w*16+15.
// ---------------------------------------------------------------------------
__global__ __launch_bounds__(256) void k_node_pre(
    const unsigned short* __restrict__ xb, const unsigned short* __restrict__ pk,
    const float* __restrict__ bh1, const float* __restrict__ Wh2,
    const float* __restrict__ bh2, const float* __restrict__ bf1,
    unsigned short* __restrict__ xfb, float* __restrict__ delta)
{
    __shared__ float hl[64 * 132];
    const int t  = threadIdx.x;
    const int w  = t >> 6, l = t & 63;
    const int lm = l & 15, q = l >> 4;
    const int row0 = blockIdx.x * 64 + w * 16;

    const unsigned short* pkh = pk;            // mat 0
    const unsigned short* pkf = pk + 16384;    // mat 1

    floatx4 hacc[8], facc[8];
    #pragma unroll
    for (int ct = 0; ct < 8; ++ct) { hacc[ct] = 0.f; facc[ct] = 0.f; }

    #pragma unroll
    for (int kc = 0; kc < 4; ++kc) {
        const short8 a = *(const short8*)(xb + (size_t)(row0 + lm) * DD + kc * 32 + q * 8);
        #pragma unroll
        for (int ct = 0; ct < 8; ++ct) {
            const short8 bh = *(const short8*)(pkh + (size_t)((ct * 4 + kc) * 64 + l) * 8);
            const short8 bf = *(const short8*)(pkf + (size_t)((ct * 4 + kc) * 64 + l) * 8);
            hacc[ct] = __builtin_amdgcn_mfma_f32_16x16x32_bf16(a, bh, hacc[ct], 0, 0, 0);
            facc[ct] = __builtin_amdgcn_mfma_f32_16x16x32_bf16(a, bf, facc[ct], 0, 0, 0);
        }
    }

    // epilogue: D layout row=(q*4+r), col=lm  (m89/m91-verified)
    #pragma unroll
    for (int ct = 0; ct < 8; ++ct) {
        const int col = ct * 16 + lm;
        const float b1 = bh1[col];
        const float bf = bf1[col];
        #pragma unroll
        for (int r = 0; r < 4; ++r) {
            const int rr = q * 4 + r;
            xfb[(size_t)(row0 + rr) * DD + col] = f2bf(facc[ct][r] + bf);
            hl[(w * 16 + rr) * 132 + col] = leaky1(hacc[ct][r] + b1);
        }
    }
    __syncthreads();

    // delta = tanh(h @ Wh2 + bh2): 64 rows x 3 outputs
    if (t < 192) {
        const int r = t / 3, k = t - 3 * (t / 3);
        float s = bh2[k];
        for (int d = 0; d < DD; ++d) s += hl[r * 132 + d] * Wh2[d * 3 + k];
        delta[(size_t)(blockIdx.x * 64 + r) * 3 + k] = tanhf(s);
    }
}

// ---------------------------------------------------------------------------
// Hierarchical exclusive scan of deg[NN] -> off[NN+1] (+cur copy).
// ---------------------------------------------------------------------------
__global__ __launch_bounds__(1024) void k_scan_up(const int* __restrict__ deg,
                                                  int* __restrict__ off,
                                                  int* __restrict__ bsum)
{
    __shared__ int wsum[16];
    const int t = threadIdx.x, b = blockIdx.x;
    const int i = b * 1024 + t;
    const int v = (i < NN) ? deg[i] : 0;
    const int lane = t & 63, w = t >> 6;

    int incl = v;
    #pragma unroll
    for (int d = 1; d < 64; d <<= 1) {
        const int o = __shfl_up(incl, d);
        if (lane >= d) incl += o;
    }
    if (lane == 63) wsum[w] = incl;
    __syncthreads();
    int wbase = 0;
    for (int k = 0; k < w; ++k) wbase += wsum[k];

    if (i < NN) off[i] = wbase + incl - v;
    if (t == 1023) bsum[b] = wbase + incl;
}

__global__ __launch_bounds__(64) void k_scan_mid(const int* __restrict__ bsum,
                                                 int* __restrict__ bbase)
{
    const int t = threadIdx.x;
    const int v = (t < 40) ? bsum[t] : 0;
    int incl = v;
    #pragma unroll
    for (int d = 1; d < 64; d <<= 1) {
        const int o = __shfl_up(incl, d);
        if (t >= d) incl += o;
    }
    if (t < 40) bbase[t] = incl - v;
}

__global__ __launch_bounds__(1024) void k_scan_add(int* __restrict__ off,
                                                   const int* __restrict__ bbase,
                                                   int* __restrict__ cur)
{
    const int t = threadIdx.x, b = blockIdx.x;
    const int i = b * 1024 + t;
    if (i < NN) {
        const int o = off[i] + bbase[b];
        off[i] = o;
        cur[i] = o;
    }
    if (i == 0) off[NN] = EE;
}

// ---------------------------------------------------------------------------
// K_scatter: bucket src indices by dst (CSR fill)
// ---------------------------------------------------------------------------
__global__ __launch_bounds__(256) void k_scatter(const int* __restrict__ ei,
                                                 int* __restrict__ cur,
                                                 int* __restrict__ esrc)
{
    const int e = blockIdx.x * 256 + threadIdx.x;
    const int src = ei[e];
    const int dst = ei[EE + e];
    const int p = atomicAdd(&cur[dst], 1);
    esrc[p] = src;
}

// ---------------------------------------------------------------------------
// K_gather: pull-mode aggregation. One wave per dst node, 2 cols/lane.
//   aggrb[n] = bf16( sum_e leaky(xfb[src_e] + rel_e @ Wf1[0:3,:]) )
//   rel_e    = pos[src_e] + (delta[n] - pos[n])
// xfb is bf16: one 4B uint load per edge per lane.
// ---------------------------------------------------------------------------
__global__ __launch_bounds__(256) void k_gather(
    const int* __restrict__ off, const int* __restrict__ esrc,
    const float* __restrict__ pos, const float* __restrict__ delta,
    const unsigned short* __restrict__ xfb, const float* __restrict__ Wf1,
    unsigned short* __restrict__ aggrb)
{
    const int t    = threadIdx.x;
    const int lane = t & 63;
    const int n    = blockIdx.x * 4 + (t >> 6);
    const int c2   = lane * 2;

    const float2 w0 = *(const float2*)(Wf1 + 0 * DD + c2);
    const float2 w1 = *(const float2*)(Wf1 + 1 * DD + c2);
    const float2 w2 = *(const float2*)(Wf1 + 2 * DD + c2);

    const float q0 = delta[n * 3 + 0] - pos[n * 3 + 0];
    const float q1 = delta[n * 3 + 1] - pos[n * 3 + 1];
    const float q2 = delta[n * 3 + 2] - pos[n * 3 + 2];

    float a0 = 0.f, a1 = 0.f;
    const int beg = off[n], end = off[n + 1];

    int j = beg;
    for (; j + 1 < end; j += 2) {
        const int s0 = esrc[j];
        const int s1 = esrc[j + 1];
        const unsigned int u0 = *(const unsigned int*)(xfb + (size_t)s0 * DD + c2);
        const unsigned int u1 = *(const unsigned int*)(xfb + (size_t)s1 * DD + c2);
        const float x00 = __uint_as_float(u0 << 16);
        const float x01 = __uint_as_float(u0 & 0xffff0000u);
        const float x10 = __uint_as_float(u1 << 16);
        const float x11 = __uint_as_float(u1 & 0xffff0000u);
        const float r00 = pos[s0 * 3 + 0] + q0;
        const float r01 = pos[s0 * 3 + 1] + q1;
        const float r02 = pos[s0 * 3 + 2] + q2;
        const float r10 = pos[s1 * 3 + 0] + q0;
        const float r11 = pos[s1 * 3 + 1] + q1;
        const float r12 = pos[s1 * 3 + 2] + q2;
        a0 += leaky1(x00 + r00 * w0.x + r01 * w1.x + r02 * w2.x);
        a1 += leaky1(x01 + r00 * w0.y + r01 * w1.y + r02 * w2.y);
        a0 += leaky1(x10 + r10 * w0.x + r11 * w1.x + r12 * w2.x);
        a1 += leaky1(x11 + r10 * w0.y + r11 * w1.y + r12 * w2.y);
    }
    if (j < end) {
        const int s0 = esrc[j];
        const unsigned int u0 = *(const unsigned int*)(xfb + (size_t)s0 * DD + c2);
        const float x00 = __uint_as_float(u0 << 16);
        const float x01 = __uint_as_float(u0 & 0xffff0000u);
        const float r00 = pos[s0 * 3 + 0] + q0;
        const float r01 = pos[s0 * 3 + 1] + q1;
        const float r02 = pos[s0 * 3 + 2] + q2;
        a0 += leaky1(x00 + r00 * w0.x + r01 * w1.x + r02 * w2.x);
        a1 += leaky1(x01 + r00 * w0.y + r01 * w1.y + r02 * w2.y);
    }

    unsigned int st = ((unsigned int)f2bf(a1) << 16) | (unsigned int)f2bf(a0);
    *(unsigned int*)(aggrb + (size_t)n * DD + c2) = st;
}

// ---------------------------------------------------------------------------
// K4: node update via MFMA.
//   g   = leaky(aggr@Wg1 + bg1)   (bf16 via LDS)
//   out = x + g@Wg2 + bg2
// Block = 256 (4 waves), 64 rows/block.
// ---------------------------------------------------------------------------
__global__ __launch_bounds__(256) void k_node_out(
    const unsigned short* __restrict__ aggrb, const unsigned short* __restrict__ pk,
    const float* __restrict__ x,
    const float* __restrict__ bg1, const float* __restrict__ bg2,
    float* __restrict__ out)
{
    __shared__ unsigned short gl[64 * 136];   // bf16 g tile, 272B row stride (16B-aligned)
    const int t  = threadIdx.x;
    const int w  = t >> 6, l = t & 63;
    const int lm = l & 15, q = l >> 4;
    const int row0 = blockIdx.x * 64 + w * 16;

    const unsigned short* pkg1 = pk + 32768;   // mat 2
    const unsigned short* pkg2 = pk + 49152;   // mat 3

    // phase 1: g = leaky(aggr @ Wg1 + bg1)
    floatx4 gacc[8];
    #pragma unroll
    for (int ct = 0; ct < 8; ++ct) gacc[ct] = 0.f;

    #pragma unroll
    for (int kc = 0; kc < 4; ++kc) {
        const short8 a = *(const short8*)(aggrb + (size_t)(row0 + lm) * DD + kc * 32 + q * 8);
        #pragma unroll
        for (int ct = 0; ct < 8; ++ct) {
            const short8 b = *(const short8*)(pkg1 + (size_t)((ct * 4 + kc) * 64 + l) * 8);
            gacc[ct] = __builtin_amdgcn_mfma_f32_16x16x32_bf16(a, b, gacc[ct], 0, 0, 0);
        }
    }

    #pragma unroll
    for (int ct = 0; ct < 8; ++ct) {
        const int col = ct * 16 + lm;
        const float b1 = bg1[col];
        #pragma unroll
        for (int r = 0; r < 4; ++r)
            gl[(w * 16 + q * 4 + r) * 136 + col] = f2bf(leaky1(gacc[ct][r] + b1));
    }
    __syncthreads();

    // phase 2: out = x + g @ Wg2 + bg2
    floatx4 oacc[8];
    #pragma unroll
    for (int ct = 0; ct < 8; ++ct) oacc[ct] = 0.f;

    #pragma unroll
    for (int kc = 0; kc < 4; ++kc) {
        const short8 a = *(const short8*)(gl + (size_t)(w * 16 + lm) * 136 + kc * 32 + q * 8);
        #pragma unroll
        for (int ct = 0; ct < 8; ++ct) {
            const short8 b = *(const short8*)(pkg2 + (size_t)((ct * 4 + kc) * 64 + l) * 8);
            oacc[ct] = __builtin_amdgcn_mfma_f32_16x16x32_bf16(a, b, oacc[ct], 0, 0, 0);
        }
    }

    #pragma unroll
    for (int ct = 0; ct < 8; ++ct) {
        const int col = ct * 16 + lm;
        const float b2 = bg2[col];
        #pragma unroll
        for (int r = 0; r < 4; ++r) {
            const size_t o = (size_t)(row0 + q * 4 + r) * DD + col;
            out[o] = x[o] + oacc[ct][r] + b2;
        }
    }
}

// ---------------------------------------------------------------------------
extern "C" void kernel_launch(void* const* d_in, const int* in_sizes, int n_in,
                              void* d_out, int out_size, void* d_ws, size_t ws_size,
                              hipStream_t stream)
{
    const float* x   = (const float*)d_in[0];
    const float* pos = (const float*)d_in[1];
    const int*   ei  = (const int*)d_in[2];
    const float* Wh1 = (const float*)d_in[3];
    const float* bh1 = (const float*)d_in[4];
    const float* Wh2 = (const float*)d_in[5];
    const float* bh2 = (const float*)d_in[6];
    const float* Wf1 = (const float*)d_in[7];
    const float* bf1 = (const float*)d_in[8];
    const float* Wg1 = (const float*)d_in[9];
    const float* bg1 = (const float*)d_in[10];
    const float* Wg2 = (const float*)d_in[11];
    const float* bg2 = (const float*)d_in[12];
    float* out = (float*)d_out;

    // workspace layout (16B-aligned segments where vector-loaded):
    unsigned short* xb    = (unsigned short*)d_ws;          // NN*DD bf16 = 10.24 MB
    unsigned short* xfb   = xb + (size_t)NN * DD;           // NN*DD bf16 = 10.24 MB
    unsigned short* aggrb = xfb + (size_t)NN * DD;          // NN*DD bf16 = 10.24 MB
    unsigned short* pk    = aggrb + (size_t)NN * DD;        // 4*16384 bf16 = 128 KB
    float* delta = (float*)(pk + 65536);                    // NN*3
    int*   deg   = (int*)(delta + (size_t)NN * 3);          // NN
    int*   off   = deg + NN;                                // NN+4 (padded)
    int*   cur   = off + NN + 4;                            // NN
    int*   esrc  = cur + NN;                                // EE
    int*   bsum  = esrc + EE;                               // 40
    int*   bbase = bsum + 40;                               // 40
    // total ~34.5 MB

    k_zero<<<40, 256, 0, stream>>>((float4*)deg, NN / 4);
    k_pack<<<32, 256, 0, stream>>>(Wh1, Wf1, Wg1, Wg2, pk);
    k_xcvt_hist<<<1250, 256, 0, stream>>>(x, ei, xb, deg);
    k_node_pre<<<NN / 64, 256, 0, stream>>>(xb, pk, bh1, Wh2, bh2, bf1, xfb, delta);
    k_scan_up<<<40, 1024, 0, stream>>>(deg, off, bsum);
    k_scan_mid<<<1, 64, 0, stream>>>(bsum, bbase);
    k_scan_add<<<40, 1024, 0, stream>>>(off, bbase, cur);
    k_scatter<<<EE / 256, 256, 0, stream>>>(ei, cur, esrc);
    k_gather<<<NN / 4, 256, 0, stream>>>(off, esrc, pos, delta, xfb, Wf1, aggrb);
    k_node_out<<<NN / 64, 256, 0, stream>>>(aggrb, pk, x, bg1, bg2, out);
}

// Round 5
// 235.336 us; speedup vs baseline: 5.5144x; 1.0363x over previous
//
#include <hip/hip_runtime.h>

#define NN 40000
#define DD 128
#define EE 640000
#define SLOPE 0.01f

typedef __attribute__((ext_vector_type(8))) short  short8;   // 8 x bf16 (4 VGPR)
typedef __attribute__((ext_vector_type(8))) unsigned short ushort8;
typedef __attribute__((ext_vector_type(4))) float  floatx4;  // MFMA acc

__device__ __forceinline__ float leaky1(float v) { return v >= 0.f ? v : v * SLOPE; }

__device__ __forceinline__ unsigned short f2bf(float f) {
    unsigned int u = __float_as_uint(f);
    u += 0x7fffu + ((u >> 16) & 1u);       // RNE
    return (unsigned short)(u >> 16);
}

// ---------------------------------------------------------------------------
// K_zero: zero a region (16B granular)
// ---------------------------------------------------------------------------
__global__ __launch_bounds__(256) void k_zero(float4* __restrict__ p, int n4)
{
    const float4 z = {0.f, 0.f, 0.f, 0.f};
    for (int i = blockIdx.x * 256 + threadIdx.x; i < n4; i += gridDim.x * 256)
        p[i] = z;
}

// ---------------------------------------------------------------------------
// K_prep: fused  (blocks 0..1249)  x->bf16 convert + deg histogram
//                (blocks 1250..1281) weight pack into MFMA B-frag order:
//   pk[mat][ct][kc][lane][j] = W[kc*32 + (lane>>4)*8 + j][ct*16 + (lane&15)]
//   mats: 0=Wh1, 1=Wf1[3:], 2=Wg1, 3=Wg2
// ---------------------------------------------------------------------------
__global__ __launch_bounds__(256) void k_prep(
    const float* __restrict__ x, const int* __restrict__ ei,
    const float* __restrict__ Wh1, const float* __restrict__ Wf1,
    const float* __restrict__ Wg1, const float* __restrict__ Wg2,
    unsigned short* __restrict__ xb, int* __restrict__ deg,
    unsigned short* __restrict__ pk)
{
    if (blockIdx.x < 1250) {
        const int gid = blockIdx.x * 256 + threadIdx.x;
        const int e0 = gid * 2;
        atomicAdd(&deg[ei[EE + e0]], 1);
        atomicAdd(&deg[ei[EE + e0 + 1]], 1);

        const size_t base = (size_t)gid * 16;
        ushort8 o0, o1;
        #pragma unroll
        for (int q = 0; q < 2; ++q) {
            #pragma unroll
            for (int p = 0; p < 2; ++p) {
                const float4 v = *(const float4*)(x + base + q * 8 + p * 4);
                ushort8& o = q ? o1 : o0;
                o[p * 4 + 0] = f2bf(v.x);
                o[p * 4 + 1] = f2bf(v.y);
                o[p * 4 + 2] = f2bf(v.z);
                o[p * 4 + 3] = f2bf(v.w);
            }
        }
        *(ushort8*)(xb + base)     = o0;
        *(ushort8*)(xb + base + 8) = o1;
    } else {
        const int t   = (blockIdx.x - 1250) * 256 + threadIdx.x;   // 0..8191
        const int mat = t >> 11;
        const int rem = t & 2047;
        const int ct  = rem >> 8;
        const int kc  = (rem >> 6) & 3;
        const int l   = rem & 63;
        const float* W = (mat == 0) ? Wh1 : (mat == 1) ? (Wf1 + 3 * DD)
                       : (mat == 2) ? Wg1 : Wg2;
        const int n  = ct * 16 + (l & 15);
        const int k0 = kc * 32 + (l >> 4) * 8;
        ushort8 v;
        #pragma unroll
        for (int j = 0; j < 8; ++j) v[j] = f2bf(W[(size_t)(k0 + j) * DD + n]);
        *(ushort8*)(pk + (size_t)t * 8) = v;
    }
}

// ---------------------------------------------------------------------------
// K1: per-node precompute via MFMA.
//   h     = leaky(x@Wh1 + bh1)                       (LDS fp32, for delta)
//   delta = tanh(h@Wh2 + bh2)                        -> global
//   u     = bf16(x@Wf1[3:] + bf1 + pos@Wf1[0:3])     -> global (coalesced via LDS)
// Block = 256 (4 waves), 64 rows/block.
// ---------------------------------------------------------------------------
__global__ __launch_bounds__(256) void k_node_pre(
    const unsigned short* __restrict__ xb, const unsigned short* __restrict__ pk,
    const float* __restrict__ pos, const float* __restrict__ Wf1,
    const float* __restrict__ bh1, const float* __restrict__ Wh2,
    const float* __restrict__ bh2, const float* __restrict__ bf1,
    unsigned short* __restrict__ ub, float* __restrict__ delta)
{
    __shared__ float          hl[64 * 132];   // h tile fp32
    __shared__ unsigned short ul[64 * 136];   // u tile bf16
    const int t  = threadIdx.x;
    const int w  = t >> 6, l = t & 63;
    const int lm = l & 15, q = l >> 4;
    const int rowb = blockIdx.x * 64;
    const int row0 = rowb + w * 16;

    const unsigned short* pkh = pk;            // mat 0
    const unsigned short* pkf = pk + 16384;    // mat 1

    floatx4 hacc[8], facc[8];
    #pragma unroll
    for (int ct = 0; ct < 8; ++ct) { hacc[ct] = 0.f; facc[ct] = 0.f; }

    #pragma unroll
    for (int kc = 0; kc < 4; ++kc) {
        const short8 a = *(const short8*)(xb + (size_t)(row0 + lm) * DD + kc * 32 + q * 8);
        #pragma unroll
        for (int ct = 0; ct < 8; ++ct) {
            const short8 bh = *(const short8*)(pkh + (size_t)((ct * 4 + kc) * 64 + l) * 8);
            const short8 bf = *(const short8*)(pkf + (size_t)((ct * 4 + kc) * 64 + l) * 8);
            hacc[ct] = __builtin_amdgcn_mfma_f32_16x16x32_bf16(a, bh, hacc[ct], 0, 0, 0);
            facc[ct] = __builtin_amdgcn_mfma_f32_16x16x32_bf16(a, bf, facc[ct], 0, 0, 0);
        }
    }

    // pos rows this lane touches (broadcast among 16 lanes of a quad)
    float px[4][3];
    #pragma unroll
    for (int r = 0; r < 4; ++r) {
        const int rr = row0 + q * 4 + r;
        px[r][0] = pos[rr * 3 + 0];
        px[r][1] = pos[rr * 3 + 1];
        px[r][2] = pos[rr * 3 + 2];
    }

    // epilogue: D layout row=(q*4+r), col=ct*16+lm  (m89/m91-verified)
    #pragma unroll
    for (int ct = 0; ct < 8; ++ct) {
        const int col = ct * 16 + lm;
        const float b1 = bh1[col];
        const float bf = bf1[col];
        const float w0 = Wf1[0 * DD + col];
        const float w1 = Wf1[1 * DD + col];
        const float w2 = Wf1[2 * DD + col];
        #pragma unroll
        for (int r = 0; r < 4; ++r) {
            const int rr = w * 16 + q * 4 + r;
            const float uv = facc[ct][r] + bf
                           + px[r][0] * w0 + px[r][1] * w1 + px[r][2] * w2;
            ul[rr * 136 + col] = f2bf(uv);
            hl[rr * 132 + col] = leaky1(hacc[ct][r] + b1);
        }
    }
    __syncthreads();

    // coalesced u store: 1024 x 16B chunks
    #pragma unroll
    for (int k = 0; k < 4; ++k) {
        const int idx = t + k * 256;
        const int row = idx >> 4;
        const int c8  = (idx & 15) * 8;
        const ushort8 vv = *(const ushort8*)(ul + row * 136 + c8);
        *(ushort8*)(ub + (size_t)(rowb + row) * DD + c8) = vv;
    }

    // delta = tanh(h @ Wh2 + bh2): 64 rows x 3 outputs
    if (t < 192) {
        const int r = t / 3, k = t - 3 * (t / 3);
        float s = bh2[k];
        for (int d = 0; d < DD; ++d) s += hl[r * 132 + d] * Wh2[d * 3 + k];
        delta[(size_t)(rowb + r) * 3 + k] = tanhf(s);
    }
}

// ---------------------------------------------------------------------------
// Hierarchical exclusive scan of deg[NN] -> off[NN+1] (+cur copy).
// ---------------------------------------------------------------------------
__global__ __launch_bounds__(1024) void k_scan_up(const int* __restrict__ deg,
                                                  int* __restrict__ off,
                                                  int* __restrict__ bsum)
{
    __shared__ int wsum[16];
    const int t = threadIdx.x, b = blockIdx.x;
    const int i = b * 1024 + t;
    const int v = (i < NN) ? deg[i] : 0;
    const int lane = t & 63, w = t >> 6;

    int incl = v;
    #pragma unroll
    for (int d = 1; d < 64; d <<= 1) {
        const int o = __shfl_up(incl, d);
        if (lane >= d) incl += o;
    }
    if (lane == 63) wsum[w] = incl;
    __syncthreads();
    int wbase = 0;
    for (int k = 0; k < w; ++k) wbase += wsum[k];

    if (i < NN) off[i] = wbase + incl - v;
    if (t == 1023) bsum[b] = wbase + incl;
}

__global__ __launch_bounds__(64) void k_scan_mid(const int* __restrict__ bsum,
                                                 int* __restrict__ bbase)
{
    const int t = threadIdx.x;
    const int v = (t < 40) ? bsum[t] : 0;
    int incl = v;
    #pragma unroll
    for (int d = 1; d < 64; d <<= 1) {
        const int o = __shfl_up(incl, d);
        if (t >= d) incl += o;
    }
    if (t < 40) bbase[t] = incl - v;
}

__global__ __launch_bounds__(1024) void k_scan_add(int* __restrict__ off,
                                                   const int* __restrict__ bbase,
                                                   int* __restrict__ cur)
{
    const int t = threadIdx.x, b = blockIdx.x;
    const int i = b * 1024 + t;
    if (i < NN) {
        const int o = off[i] + bbase[b];
        off[i] = o;
        cur[i] = o;
    }
    if (i == 0) off[NN] = EE;
}

// ---------------------------------------------------------------------------
// K_scatter: bucket src indices by dst (CSR fill)
// ---------------------------------------------------------------------------
__global__ __launch_bounds__(256) void k_scatter(const int* __restrict__ ei,
                                                 int* __restrict__ cur,
                                                 int* __restrict__ esrc)
{
    const int e = blockIdx.x * 256 + threadIdx.x;
    const int src = ei[e];
    const int dst = ei[EE + e];
    const int p = atomicAdd(&cur[dst], 1);
    esrc[p] = src;
}

// ---------------------------------------------------------------------------
// K_gather: pull-mode aggregation. One wave per dst node, 2 cols/lane.
//   v        = (delta[n]-pos[n]) @ Wf1[0:3,:]          (once per node)
//   aggrb[n] = bf16( sum_e leaky(ub[src_e] + v) )
// Inner loop: 1 gathered dword + ~10 VALU per edge per lane.
// ---------------------------------------------------------------------------
__global__ __launch_bounds__(256) void k_gather(
    const int* __restrict__ off, const int* __restrict__ esrc,
    const float* __restrict__ pos, const float* __restrict__ delta,
    const float* __restrict__ Wf1, const unsigned short* __restrict__ ub,
    unsigned short* __restrict__ aggrb)
{
    const int t    = threadIdx.x;
    const int lane = t & 63;
    const int n    = blockIdx.x * 4 + (t >> 6);
    const int c2   = lane * 2;

    const float2 w0 = *(const float2*)(Wf1 + 0 * DD + c2);
    const float2 w1 = *(const float2*)(Wf1 + 1 * DD + c2);
    const float2 w2 = *(const float2*)(Wf1 + 2 * DD + c2);

    const float q0 = delta[n * 3 + 0] - pos[n * 3 + 0];
    const float q1 = delta[n * 3 + 1] - pos[n * 3 + 1];
    const float q2 = delta[n * 3 + 2] - pos[n * 3 + 2];

    const float v0 = q0 * w0.x + q1 * w1.x + q2 * w2.x;
    const float v1 = q0 * w0.y + q1 * w1.y + q2 * w2.y;

    float a0 = 0.f, a1 = 0.f, b0 = 0.f, b1 = 0.f;
    const int beg = off[n], end = off[n + 1];

#define EDGE_ACC(U, A0, A1)                                            \
    {                                                                  \
        const float e0 = __uint_as_float((U) << 16) + v0;              \
        const float e1 = __uint_as_float((U) & 0xffff0000u) + v1;      \
        A0 += leaky1(e0);                                              \
        A1 += leaky1(e1);                                              \
    }

    int j = beg;
    for (; j + 3 < end; j += 4) {
        const int s0 = esrc[j];
        const int s1 = esrc[j + 1];
        const int s2 = esrc[j + 2];
        const int s3 = esrc[j + 3];
        const unsigned int u0 = *(const unsigned int*)(ub + (size_t)s0 * DD + c2);
        const unsigned int u1 = *(const unsigned int*)(ub + (size_t)s1 * DD + c2);
        const unsigned int u2 = *(const unsigned int*)(ub + (size_t)s2 * DD + c2);
        const unsigned int u3 = *(const unsigned int*)(ub + (size_t)s3 * DD + c2);
        EDGE_ACC(u0, a0, a1)
        EDGE_ACC(u1, b0, b1)
        EDGE_ACC(u2, a0, a1)
        EDGE_ACC(u3, b0, b1)
    }
    for (; j < end; ++j) {
        const int s0 = esrc[j];
        const unsigned int u0 = *(const unsigned int*)(ub + (size_t)s0 * DD + c2);
        EDGE_ACC(u0, a0, a1)
    }
#undef EDGE_ACC

    a0 += b0; a1 += b1;
    unsigned int st = ((unsigned int)f2bf(a1) << 16) | (unsigned int)f2bf(a0);
    *(unsigned int*)(aggrb + (size_t)n * DD + c2) = st;
}

// ---------------------------------------------------------------------------
// K4: node update via MFMA.
//   g   = leaky(aggr@Wg1 + bg1)   (bf16 via LDS)
//   out = x + g@Wg2 + bg2         (coalesced via LDS)
// Block = 256 (4 waves), 64 rows/block.
// ---------------------------------------------------------------------------
__global__ __launch_bounds__(256) void k_node_out(
    const unsigned short* __restrict__ aggrb, const unsigned short* __restrict__ pk,
    const float* __restrict__ x,
    const float* __restrict__ bg1, const float* __restrict__ bg2,
    float* __restrict__ out)
{
    __shared__ unsigned short gl[64 * 136];   // bf16 g tile
    __shared__ float          ol[64 * 132];   // fp32 o tile
    const int t  = threadIdx.x;
    const int w  = t >> 6, l = t & 63;
    const int lm = l & 15, q = l >> 4;
    const int rowb = blockIdx.x * 64;
    const int row0 = rowb + w * 16;

    const unsigned short* pkg1 = pk + 32768;   // mat 2
    const unsigned short* pkg2 = pk + 49152;   // mat 3

    // phase 1: g = leaky(aggr @ Wg1 + bg1)
    floatx4 gacc[8];
    #pragma unroll
    for (int ct = 0; ct < 8; ++ct) gacc[ct] = 0.f;

    #pragma unroll
    for (int kc = 0; kc < 4; ++kc) {
        const short8 a = *(const short8*)(aggrb + (size_t)(row0 + lm) * DD + kc * 32 + q * 8);
        #pragma unroll
        for (int ct = 0; ct < 8; ++ct) {
            const short8 b = *(const short8*)(pkg1 + (size_t)((ct * 4 + kc) * 64 + l) * 8);
            gacc[ct] = __builtin_amdgcn_mfma_f32_16x16x32_bf16(a, b, gacc[ct], 0, 0, 0);
        }
    }

    #pragma unroll
    for (int ct = 0; ct < 8; ++ct) {
        const int col = ct * 16 + lm;
        const float b1 = bg1[col];
        #pragma unroll
        for (int r = 0; r < 4; ++r)
            gl[(w * 16 + q * 4 + r) * 136 + col] = f2bf(leaky1(gacc[ct][r] + b1));
    }
    __syncthreads();

    // phase 2: o = g @ Wg2
    floatx4 oacc[8];
    #pragma unroll
    for (int ct = 0; ct < 8; ++ct) oacc[ct] = 0.f;

    #pragma unroll
    for (int kc = 0; kc < 4; ++kc) {
        const short8 a = *(const short8*)(gl + (size_t)(w * 16 + lm) * 136 + kc * 32 + q * 8);
        #pragma unroll
        for (int ct = 0; ct < 8; ++ct) {
            const short8 b = *(const short8*)(pkg2 + (size_t)((ct * 4 + kc) * 64 + l) * 8);
            oacc[ct] = __builtin_amdgcn_mfma_f32_16x16x32_bf16(a, b, oacc[ct], 0, 0, 0);
        }
    }

    __syncthreads();   // all gl reads done
    #pragma unroll
    for (int ct = 0; ct < 8; ++ct) {
        const int col = ct * 16 + lm;
        #pragma unroll
        for (int r = 0; r < 4; ++r)
            ol[(w * 16 + q * 4 + r) * 132 + col] = oacc[ct][r];
    }
    __syncthreads();

    // coalesced epilogue: out = x + o + bg2, 2048 x 16B chunks
    #pragma unroll
    for (int k = 0; k < 8; ++k) {
        const int idx = t + k * 256;
        const int row = idx >> 5;
        const int c4  = (idx & 31) * 4;
        const float4 ov = *(const float4*)(ol + row * 132 + c4);
        const float4 bv = *(const float4*)(bg2 + c4);
        const size_t o  = (size_t)(rowb + row) * DD + c4;
        const float4 xv = *(const float4*)(x + o);
        float4 rv;
        rv.x = xv.x + ov.x + bv.x;
        rv.y = xv.y + ov.y + bv.y;
        rv.z = xv.z + ov.z + bv.z;
        rv.w = xv.w + ov.w + bv.w;
        *(float4*)(out + o) = rv;
    }
}

// ---------------------------------------------------------------------------
extern "C" void kernel_launch(void* const* d_in, const int* in_sizes, int n_in,
                              void* d_out, int out_size, void* d_ws, size_t ws_size,
                              hipStream_t stream)
{
    const float* x   = (const float*)d_in[0];
    const float* pos = (const float*)d_in[1];
    const int*   ei  = (const int*)d_in[2];
    const float* Wh1 = (const float*)d_in[3];
    const float* bh1 = (const float*)d_in[4];
    const float* Wh2 = (const float*)d_in[5];
    const float* bh2 = (const float*)d_in[6];
    const float* Wf1 = (const float*)d_in[7];
    const float* bf1 = (const float*)d_in[8];
    const float* Wg1 = (const float*)d_in[9];
    const float* bg1 = (const float*)d_in[10];
    const float* Wg2 = (const float*)d_in[11];
    const float* bg2 = (const float*)d_in[12];
    float* out = (float*)d_out;

    unsigned short* xb    = (unsigned short*)d_ws;          // NN*DD bf16
    unsigned short* ub    = xb + (size_t)NN * DD;           // NN*DD bf16
    unsigned short* aggrb = ub + (size_t)NN * DD;           // NN*DD bf16
    unsigned short* pk    = aggrb + (size_t)NN * DD;        // 4*16384 bf16
    float* delta = (float*)(pk + 65536);                    // NN*3
    int*   deg   = (int*)(delta + (size_t)NN * 3);          // NN
    int*   off   = deg + NN;                                // NN+4
    int*   cur   = off + NN + 4;                            // NN
    int*   esrc  = cur + NN;                                // EE
    int*   bsum  = esrc + EE;                               // 40
    int*   bbase = bsum + 40;                               // 40

    k_zero<<<40, 256, 0, stream>>>((float4*)deg, NN / 4);
    k_prep<<<1282, 256, 0, stream>>>(x, ei, Wh1, Wf1, Wg1, Wg2, xb, deg, pk);
    k_node_pre<<<NN / 64, 256, 0, stream>>>(xb, pk, pos, Wf1, bh1, Wh2, bh2, bf1,
                                            ub, delta);
    k_scan_up<<<40, 1024, 0, stream>>>(deg, off, bsum);
    k_scan_mid<<<1, 64, 0, stream>>>(bsum, bbase);
    k_scan_add<<<40, 1024, 0, stream>>>(off, bbase, cur);
    k_scatter<<<EE / 256, 256, 0, stream>>>(ei, cur, esrc);
    k_gather<<<NN / 4, 256, 0, stream>>>(off, esrc, pos, delta, Wf1, ub, aggrb);
    k_node_out<<<NN / 64, 256, 0, stream>>>(aggrb, pk, x, bg1, bg2, out);
}